// Round 1
// baseline (518.619 us; speedup 1.0000x reference)
//
#include <hip/hip_runtime.h>

#define ALPHA 0.9f
#define BETA  0.8f
#define K     25
#define B     128
#define T     16
#define IN_DIM 14400

// Layer dims and cumulative offsets (in neurons) into the packed state buffers.
__constant__ int g_dummy; // (unused)

// ---------------------------------------------------------------------------
// Transpose x (B, T, IN_DIM) -> xT (T, IN_DIM, B) so layer-0 gathers are
// coalesced along the batch (lane) dimension. Tiled 64x64 via LDS (+1 pad).
// ---------------------------------------------------------------------------
__global__ __launch_bounds__(256) void transpose_x_kernel(
    const float* __restrict__ x, float* __restrict__ xT) {
  __shared__ float tile[64][65];
  const int t  = blockIdx.z;
  const int i0 = blockIdx.x * 64;   // input-feature tile
  const int b0 = blockIdx.y * 64;   // batch tile
  const int lane = threadIdx.x & 63;
  const int r0   = threadIdx.x >> 6;  // 0..3
#pragma unroll
  for (int r = 0; r < 64; r += 4) {
    const int rb = r + r0;  // batch row
    tile[rb][lane] =
        x[(size_t)(b0 + rb) * (T * IN_DIM) + (size_t)t * IN_DIM + i0 + lane];
  }
  __syncthreads();
#pragma unroll
  for (int r = 0; r < 64; r += 4) {
    const int ri = r + r0;  // feature row
    xT[((size_t)t * IN_DIM + (i0 + ri)) * B + b0 + lane] = tile[lane][ri];
  }
}

// ---------------------------------------------------------------------------
// One LCN + LIF layer step. hprev layout: [d_prev][B]. State layout: [d][B].
// One thread per (neuron d, batch b); lanes = batch -> coalesced gathers.
// knn/w/bias are wave-uniform -> scalar loads via readfirstlane'd index.
// ---------------------------------------------------------------------------
__global__ __launch_bounds__(256) void lcn_layer_kernel(
    const float* __restrict__ hprev, const float* __restrict__ w,
    const float* __restrict__ bias, const int* __restrict__ knn,
    float* __restrict__ syn, float* __restrict__ mem) {
  const int gtid = blockIdx.x * 256 + threadIdx.x;
  const int d = __builtin_amdgcn_readfirstlane(gtid >> 7);  // wave-uniform
  const int b = gtid & 127;
  const int* kp = knn + d * K;
  const float* wp = w + d * K;
  float acc = bias[d];
#pragma unroll
  for (int k = 0; k < K; ++k) {
    acc += wp[k] * hprev[(size_t)kp[k] * B + b];
  }
  const float s  = syn[gtid] * ALPHA + acc;
  const float m0 = mem[gtid];
  const float m  = BETA * m0 + s - ((m0 > 1.0f) ? 1.0f : 0.0f);
  syn[gtid] = s;
  mem[gtid] = m;
}

// Fallback layer-0 (reads x directly, un-transposed) if ws too small for xT.
__global__ __launch_bounds__(256) void lcn_layer0_direct_kernel(
    const float* __restrict__ x, int t, const float* __restrict__ w,
    const float* __restrict__ bias, const int* __restrict__ knn,
    float* __restrict__ syn, float* __restrict__ mem) {
  const int gtid = blockIdx.x * 256 + threadIdx.x;
  const int d = __builtin_amdgcn_readfirstlane(gtid >> 7);
  const int b = gtid & 127;
  const int* kp = knn + d * K;
  const float* wp = w + d * K;
  const float* xrow = x + (size_t)b * (T * IN_DIM) + (size_t)t * IN_DIM;
  float acc = bias[d];
#pragma unroll
  for (int k = 0; k < K; ++k) acc += wp[k] * xrow[kp[k]];
  const float s  = syn[gtid] * ALPHA + acc;
  const float m0 = mem[gtid];
  const float m  = BETA * m0 + s - ((m0 > 1.0f) ? 1.0f : 0.0f);
  syn[gtid] = s;
  mem[gtid] = m;
}

// Final FC on the last timestep's layer-4 membrane. out[b][j], j in {0,1}.
__global__ __launch_bounds__(128) void fc_kernel(
    const float* __restrict__ mem4,  // [450][B]
    const float* __restrict__ fc_w,  // [2][450]
    const float* __restrict__ fc_b,  // [2]
    float* __restrict__ out) {       // [B][2]
  const int b = threadIdx.x;  // 128 threads
  float a0 = fc_b[0], a1 = fc_b[1];
  for (int d = 0; d < 450; ++d) {
    const float h = mem4[d * B + b];
    a0 += fc_w[d] * h;
    a1 += fc_w[450 + d] * h;
  }
  out[b * 2 + 0] = a0;
  out[b * 2 + 1] = a1;
}

extern "C" void kernel_launch(void* const* d_in, const int* in_sizes, int n_in,
                              void* d_out, int out_size, void* d_ws,
                              size_t ws_size, hipStream_t stream) {
  (void)in_sizes; (void)n_in; (void)out_size;
  // setup_inputs() dict order: x, then per layer i: w{i}, b{i}, knn{i}, then fc_w, fc_b.
  const float* x = (const float*)d_in[0];
  const float* w[5];
  const float* bias[5];
  const int* knn[5];
  for (int i = 0; i < 5; ++i) {
    w[i]    = (const float*)d_in[1 + 3 * i];
    bias[i] = (const float*)d_in[2 + 3 * i];
    knn[i]  = (const int*)d_in[3 + 3 * i];
  }
  const float* fc_w = (const float*)d_in[16];
  const float* fc_b = (const float*)d_in[17];
  float* out = (float*)d_out;

  static const int DIMS[5] = {7200, 3600, 1800, 900, 450};
  static const int OFFS[5] = {0, 7200, 10800, 12600, 13500};  // cumulative
  const size_t xT_elems    = (size_t)T * IN_DIM * B;          // 29,491,200
  const size_t state_elems = 13950UL * B;                     // 1,785,600
  const size_t need_fast   = (xT_elems + 2 * state_elems) * sizeof(float);

  float *xT = nullptr, *syn, *mem;
  const bool fast = ws_size >= need_fast;
  if (fast) {
    xT  = (float*)d_ws;
    syn = xT + xT_elems;
    mem = syn + state_elems;
  } else {
    syn = (float*)d_ws;
    mem = syn + state_elems;
  }

  // Zero LIF state every call (harness does not re-poison between replays,
  // and we must be deterministic regardless).
  hipMemsetAsync(syn, 0, 2 * state_elems * sizeof(float), stream);

  if (fast) {
    transpose_x_kernel<<<dim3(IN_DIM / 64, B / 64, T), 256, 0, stream>>>(x, xT);
  }

  for (int t = 0; t < T; ++t) {
    for (int i = 0; i < 5; ++i) {
      const int grid = DIMS[i] * B / 256;
      float* syn_i = syn + (size_t)OFFS[i] * B;
      float* mem_i = mem + (size_t)OFFS[i] * B;
      if (i == 0) {
        if (fast) {
          lcn_layer_kernel<<<grid, 256, 0, stream>>>(
              xT + (size_t)t * IN_DIM * B, w[0], bias[0], knn[0], syn_i, mem_i);
        } else {
          lcn_layer0_direct_kernel<<<grid, 256, 0, stream>>>(
              x, t, w[0], bias[0], knn[0], syn_i, mem_i);
        }
      } else {
        const float* hp = mem + (size_t)OFFS[i - 1] * B;
        lcn_layer_kernel<<<grid, 256, 0, stream>>>(hp, w[i], bias[i], knn[i],
                                                   syn_i, mem_i);
      }
    }
  }

  fc_kernel<<<1, 128, 0, stream>>>(mem + (size_t)OFFS[4] * B, fc_w, fc_b, out);
}

// Round 2
// 418.867 us; speedup vs baseline: 1.2381x; 1.2381x over previous
//
#include <hip/hip_runtime.h>

#define ALPHA 0.9f
#define BETA  0.8f
#define K     25
#define B     128
#define T     16
#define IN_DIM 14400

// ---------------------------------------------------------------------------
// Transpose one 8-timestep slab of x: (B, T, IN) slab [t0,t0+8) -> xTh
// [8][IN_DIM][B]. float4 on both global sides; LDS 64x65 tile (2-way max
// bank aliasing = free on CDNA4).
// ---------------------------------------------------------------------------
__global__ __launch_bounds__(256) void transpose_x4_kernel(
    const float* __restrict__ x, float* __restrict__ xTh, int t0) {
  __shared__ float tile[64][65];
  const int tl = blockIdx.z;            // local t 0..7
  const int t  = t0 + tl;
  const int i0 = blockIdx.x * 64;       // feature tile
  const int b0 = blockIdx.y * 64;       // batch tile
  const int tid = threadIdx.x;

  const int fi = (tid & 15) * 4;        // feature quad
  const int bi = tid >> 4;              // batch row 0..15
#pragma unroll
  for (int p = 0; p < 4; ++p) {
    const int b = bi + p * 16;
    const float4 v = *(const float4*)&x[(size_t)(b0 + b) * (T * IN_DIM) +
                                        (size_t)t * IN_DIM + i0 + fi];
    tile[fi + 0][b] = v.x;
    tile[fi + 1][b] = v.y;
    tile[fi + 2][b] = v.z;
    tile[fi + 3][b] = v.w;
  }
  __syncthreads();
  const int bq = (tid & 15) * 4;        // batch quad
  const int fr = tid >> 4;              // feature row 0..15
#pragma unroll
  for (int p = 0; p < 4; ++p) {
    const int f = fr + p * 16;
    float4 v;
    v.x = tile[f][bq + 0];
    v.y = tile[f][bq + 1];
    v.z = tile[f][bq + 2];
    v.w = tile[f][bq + 3];
    *(float4*)&xTh[((size_t)tl * IN_DIM + (i0 + f)) * B + b0 + bq] = v;
  }
}

// ---------------------------------------------------------------------------
// One LCN+LIF layer over nt timesteps in a single kernel.
// hsrc: [nt][dprev][B]   memout: [nt][d][B]   thread = (d, b), t looped.
// syn/mem live in registers; optional state save/restore for split layer 0.
// d is wave-uniform (lanes = batch) -> knn/w/bias ride the scalar pipe;
// gathers are fully coalesced (64 lanes x 4B contiguous).
// ---------------------------------------------------------------------------
__global__ __launch_bounds__(256) void lcn_layer_allt_kernel(
    const float* __restrict__ hsrc, const float* __restrict__ w,
    const float* __restrict__ bias, const int* __restrict__ knn,
    float* __restrict__ memout, float* __restrict__ state,
    int dB, int dprevB, int nt, int load_state, int save_state) {
  const int gtid = blockIdx.x * 256 + threadIdx.x;
  const int d = __builtin_amdgcn_readfirstlane(gtid >> 7);  // wave-uniform
  const int b = gtid & 127;

  int   idx[K];
  float wr[K];
#pragma unroll
  for (int k = 0; k < K; ++k) {
    idx[k] = knn[d * K + k] * B;
    wr[k]  = w[d * K + k];
  }
  const float bi = bias[d];

  float s = 0.f, m = 0.f;
  if (load_state) {
    s = state[gtid];
    m = state[dB + gtid];
  }

  for (int t = 0; t < nt; ++t) {
    const float* hp = hsrc + (size_t)t * dprevB;
    float acc = bi;
#pragma unroll
    for (int k = 0; k < K; ++k) acc = fmaf(wr[k], hp[idx[k] + b], acc);
    s = ALPHA * s + acc;
    const float r = (m > 1.0f) ? 1.0f : 0.0f;  // reset from PREVIOUS mem
    m = BETA * m + s - r;
    memout[(size_t)t * dB + gtid] = m;
  }

  if (save_state) {
    state[gtid]      = s;
    state[dB + gtid] = m;
  }
}

// Final FC on the last timestep's layer-4 membrane. out[b][j], j in {0,1}.
__global__ __launch_bounds__(128) void fc_kernel(
    const float* __restrict__ mem4,  // [450][B]
    const float* __restrict__ fc_w,  // [2][450]
    const float* __restrict__ fc_b,  // [2]
    float* __restrict__ out) {       // [B][2]
  const int b = threadIdx.x;
  float a0 = fc_b[0], a1 = fc_b[1];
  for (int d = 0; d < 450; ++d) {
    const float h = mem4[d * B + b];
    a0 += fc_w[d] * h;
    a1 += fc_w[450 + d] * h;
  }
  out[b * 2 + 0] = a0;
  out[b * 2 + 1] = a1;
}

extern "C" void kernel_launch(void* const* d_in, const int* in_sizes, int n_in,
                              void* d_out, int out_size, void* d_ws,
                              size_t ws_size, hipStream_t stream) {
  (void)in_sizes; (void)n_in; (void)out_size; (void)ws_size;
  const float* x = (const float*)d_in[0];
  const float* w[5];
  const float* bias[5];
  const int* knn[5];
  for (int i = 0; i < 5; ++i) {
    w[i]    = (const float*)d_in[1 + 3 * i];
    bias[i] = (const float*)d_in[2 + 3 * i];
    knn[i]  = (const int*)d_in[3 + 3 * i];
  }
  const float* fc_w = (const float*)d_in[16];
  const float* fc_b = (const float*)d_in[17];
  float* out = (float*)d_out;

  static const int DIMS[5] = {7200, 3600, 1800, 900, 450};

  // Workspace layout (floats). Confirmed ws >= 132.2 MB from round 1.
  //   A    : 16*7200*128      = 14,745,600  (mem0, then mem2, then mem4)
  //   XB   : 8*14400*128      = 14,745,600  (xT half-slab; later mem1 + mem3)
  //   S    : 2*7200*128       =  1,843,200  (layer-0 syn/mem carry)
  // Total 31,334,400 floats = 125.3 MB.
  float* A  = (float*)d_ws;
  float* XB = A + 14745600;
  float* S  = XB + 14745600;

  float* mem0 = A;                    // [16][7200][128]
  float* mem1 = XB;                   // [16][3600][128] (after xT is dead)
  float* mem2 = A;                    // [16][1800][128] (mem0 dead)
  float* mem3 = XB + 7372800;         // [16][900][128]  (fits after mem1)
  float* mem4 = A;                    // [16][450][128]  (mem2 dead)

  const int inB = IN_DIM * B;

  // ---- Layer 0 in two 8-timestep stages (xT half-slab reuse) ----
  for (int stage = 0; stage < 2; ++stage) {
    const int t0 = stage * 8;
    transpose_x4_kernel<<<dim3(IN_DIM / 64, B / 64, 8), 256, 0, stream>>>(
        x, XB, t0);
    const int dB = DIMS[0] * B;
    lcn_layer_allt_kernel<<<dB / 256, 256, 0, stream>>>(
        XB, w[0], bias[0], knn[0], mem0 + (size_t)t0 * dB, S, dB, inB, 8,
        /*load=*/stage, /*save=*/stage == 0);
  }

  // ---- Layers 1..4, all 16 timesteps each ----
  const float* src = mem0;
  float* dsts[4] = {mem1, mem2, mem3, mem4};
  for (int i = 1; i < 5; ++i) {
    const int dB     = DIMS[i] * B;
    const int dprevB = DIMS[i - 1] * B;
    lcn_layer_allt_kernel<<<dB / 256, 256, 0, stream>>>(
        src, w[i], bias[i], knn[i], dsts[i - 1], nullptr, dB, dprevB, 16, 0,
        0);
    src = dsts[i - 1];
  }

  fc_kernel<<<1, 128, 0, stream>>>(mem4 + (size_t)15 * DIMS[4] * B, fc_w,
                                   fc_b, out);
}